// Round 5
// baseline (329.328 us; speedup 1.0000x reference)
//
#include <hip/hip_runtime.h>
#include <stdint.h>

#define D_INC 512
#define D_HC  512
#define D_OC  128
#define N_EXPC 16
#define BROWS 65536
#define BM2   64                // gemm2 row-tile
#define MAXTILES 1040           // 16 + 65536/64

typedef __bf16 bf16x8 __attribute__((ext_vector_type(8)));
typedef float f32x4 __attribute__((ext_vector_type(4)));
typedef unsigned int u32x4 __attribute__((ext_vector_type(4)));
typedef unsigned short u16x8 __attribute__((ext_vector_type(8)));

__device__ __forceinline__ unsigned short f2bf(float f) {
    __bf16 b = (__bf16)f;
    return __builtin_bit_cast(unsigned short, b);
}

__device__ __forceinline__ f32x4 mfma_bf16(bf16x8 a, bf16x8 b, f32x4 c) {
    return __builtin_amdgcn_mfma_f32_16x16x32_bf16(a, b, c, 0, 0, 0);
}

__device__ __forceinline__ void gl16(const unsigned short* g, unsigned short* l) {
    __builtin_amdgcn_global_load_lds(
        (const __attribute__((address_space(1))) void*)g,
        (__attribute__((address_space(3))) void*)l, 16, 0, 0);
}

// ---------------------------------------------------------------------------
// K0: transpose + f32->bf16.  src [R][C] f32 -> dst [C][R] bf16 (batched .z)
// ---------------------------------------------------------------------------
__global__ __launch_bounds__(256) void k_transpose_bf16(
    const float* __restrict__ src, unsigned short* __restrict__ dst,
    int R, int C, long sstride, long dstride)
{
    __shared__ unsigned short tile[64][72];
    src += (size_t)blockIdx.z * sstride;
    dst += (size_t)blockIdx.z * dstride;
    int r0 = blockIdx.x * 64, c0 = blockIdx.y * 64;
    int t = threadIdx.x;
    {
        int r = t >> 2, cc = (t & 3) * 16;
        const float4* p = (const float4*)(src + (size_t)(r0 + r) * C + c0 + cc);
        #pragma unroll
        for (int i = 0; i < 4; i++) {
            float4 v = p[i];
            tile[r][cc + i * 4 + 0] = f2bf(v.x);
            tile[r][cc + i * 4 + 1] = f2bf(v.y);
            tile[r][cc + i * 4 + 2] = f2bf(v.z);
            tile[r][cc + i * 4 + 3] = f2bf(v.w);
        }
    }
    __syncthreads();
    {
        int c = t >> 2, rr = (t & 3) * 16;
        unsigned short buf[16];
        #pragma unroll
        for (int i = 0; i < 16; i++) buf[i] = tile[rr + i][c];
        u16x8* q = (u16x8*)(dst + (size_t)(c0 + c) * R + r0 + rr);
        q[0] = *(u16x8*)&buf[0];
        q[1] = *(u16x8*)&buf[8];
    }
}

// ---------------------------------------------------------------------------
// Bucketing: e[i] = c[num[i]]; counts -> offsets -> scatter idx
// ---------------------------------------------------------------------------
__global__ __launch_bounds__(256) void k_hist(
    const int* __restrict__ num, const int* __restrict__ c, int* __restrict__ cnt)
{
    __shared__ int lh[N_EXPC];
    int t = threadIdx.x;
    if (t < N_EXPC) lh[t] = 0;
    __syncthreads();
    for (int i = blockIdx.x * 256 + t; i < BROWS; i += gridDim.x * 256)
        atomicAdd(&lh[c[num[i]]], 1);
    __syncthreads();
    if (t < N_EXPC) atomicAdd(&cnt[t], lh[t]);
}

// one block, 64 threads. base[e] = exclusive prefix; tbl[j] = {e, start, n}
__global__ __launch_bounds__(64) void k_scan(
    const int* __restrict__ cnt, int* __restrict__ base, int* __restrict__ tbl)
{
    __shared__ int sc[N_EXPC];
    int t = threadIdx.x;
    for (int j = t; j < MAXTILES; j += 64) tbl[j * 3 + 2] = 0;
    if (t < N_EXPC) sc[t] = cnt[t];
    __syncthreads();
    if (t < N_EXPC) {
        int run = 0, trun = 0;
        for (int e = 0; e < t; e++) { run += sc[e]; trun += (sc[e] + BM2 - 1) / BM2; }
        base[t] = run;
        int ce = sc[t];
        for (int k = 0, j = trun; k < ce; k += BM2, j++) {
            tbl[j * 3 + 0] = t;
            tbl[j * 3 + 1] = run + k;
            tbl[j * 3 + 2] = (ce - k < BM2) ? (ce - k) : BM2;
        }
    }
}

__global__ __launch_bounds__(256) void k_scatter(
    const int* __restrict__ num, const int* __restrict__ c,
    int* __restrict__ base, int* __restrict__ idx)
{
    __shared__ int lh[N_EXPC], lbase[N_EXPC];
    int t = threadIdx.x;
    if (t < N_EXPC) lh[t] = 0;
    __syncthreads();
    int i = blockIdx.x * 256 + t;               // grid == 256 blocks exactly
    int e = c[num[i]];
    int lo = atomicAdd(&lh[e], 1);
    __syncthreads();
    if (t < N_EXPC) lbase[t] = atomicAdd(&base[t], lh[t]);
    __syncthreads();
    idx[lbase[e] + lo] = i;
}

// ---------------------------------------------------------------------------
// K1: h = relu(x @ W1 + b1). 128x128 tile, BK=32, double-buffered 2-phase:
// issue stage(k+1) BEFORE compute(k); one barrier per K-step (T3 minimum).
// ---------------------------------------------------------------------------
__global__ __launch_bounds__(256, 2) void k_gemm1(
    const float* __restrict__ x, const unsigned short* __restrict__ w1t,
    const float* __restrict__ b1, unsigned short* __restrict__ h)
{
    __shared__ unsigned short lsA[2][128 * 32];
    __shared__ unsigned short lsB[2][128 * 32];

    int bid = blockIdx.x;                       // 2048 % 8 == 0 -> bijective
    int logical = (bid & 7) * 256 + (bid >> 3); // XCD-chunked swizzle
    int rb = logical >> 2, cb = logical & 3;
    long bm = (long)rb * 128;
    int bn = cb * 128;

    int t = threadIdx.x;
    int l = t & 63, wid = t >> 6;
    int wr = (wid >> 1) * 64, wc = (wid & 1) * 64;
    int lr = l & 15, kc = (l >> 4) * 8;
    int srow = t >> 1, sc = (t & 1) * 16;

    const unsigned short* bsrc0 =
        w1t + (size_t)(bn + wid * 32 + (l >> 2)) * D_INC + (l & 3) * 8;
    const unsigned short* bsrc1 = bsrc0 + (size_t)16 * D_INC;
    const float* xrow = x + (bm + srow) * D_INC + sc;

    f32x4 acc[4][4];
    #pragma unroll
    for (int i = 0; i < 4; i++)
        #pragma unroll
        for (int j = 0; j < 4; j++) acc[i][j] = (f32x4){0.f, 0.f, 0.f, 0.f};

    float4 xv0, xv1, xv2, xv3;                  // A-tile in flight (regs)
    auto loadA = [&](int k0) {
        const float4* xp = (const float4*)(xrow + k0);
        xv0 = xp[0]; xv1 = xp[1]; xv2 = xp[2]; xv3 = xp[3];
    };
    auto writeA = [&](int buf) {
        u16x8 p0, p1;
        p0[0] = f2bf(xv0.x); p0[1] = f2bf(xv0.y); p0[2] = f2bf(xv0.z); p0[3] = f2bf(xv0.w);
        p0[4] = f2bf(xv1.x); p0[5] = f2bf(xv1.y); p0[6] = f2bf(xv1.z); p0[7] = f2bf(xv1.w);
        p1[0] = f2bf(xv2.x); p1[1] = f2bf(xv2.y); p1[2] = f2bf(xv2.z); p1[3] = f2bf(xv2.w);
        p1[4] = f2bf(xv3.x); p1[5] = f2bf(xv3.y); p1[6] = f2bf(xv3.z); p1[7] = f2bf(xv3.w);
        *(u16x8*)&lsA[buf][srow * 32 + sc] = p0;
        *(u16x8*)&lsA[buf][srow * 32 + sc + 8] = p1;
    };
    auto stageB = [&](int buf, int k0) {
        gl16(bsrc0 + k0, &lsB[buf][(wid * 32) * 32]);
        gl16(bsrc1 + k0, &lsB[buf][(wid * 32 + 16) * 32]);
    };

    loadA(0); stageB(0, 0); writeA(0);
    __syncthreads();
    #pragma unroll 2
    for (int ks = 0; ks < 16; ks++) {
        int cur = ks & 1;
        if (ks < 15) {                          // issue next-tile VMEM early
            loadA((ks + 1) * 32);
            stageB(cur ^ 1, (ks + 1) * 32);
        }
        bf16x8 af[4], bfr[4];
        #pragma unroll
        for (int i = 0; i < 4; i++) {
            af[i]  = __builtin_bit_cast(bf16x8, *(const u32x4*)&lsA[cur][(wr + i * 16 + lr) * 32 + kc]);
            bfr[i] = __builtin_bit_cast(bf16x8, *(const u32x4*)&lsB[cur][(wc + i * 16 + lr) * 32 + kc]);
        }
        #pragma unroll
        for (int i = 0; i < 4; i++)
            #pragma unroll
            for (int j = 0; j < 4; j++)
                acc[i][j] = mfma_bf16(af[i], bfr[j], acc[i][j]);
        if (ks < 15) writeA(cur ^ 1);           // cvt+ds_write after MFMA
        __syncthreads();                        // drains vmcnt+lgkm once/iter
    }

    #pragma unroll
    for (int j = 0; j < 4; j++) {
        int col = bn + wc + j * 16 + lr;
        float bv = b1[col];
        #pragma unroll
        for (int i = 0; i < 4; i++) {
            long row = bm + wr + i * 16 + (l >> 4) * 4;
            #pragma unroll
            for (int r = 0; r < 4; r++) {
                float v = fmaxf(acc[i][j][r] + bv, 0.f);
                h[(row + r) * D_HC + col] = f2bf(v);
            }
        }
    }
}

// ---------------------------------------------------------------------------
// K2g: grouped routed head. Block j: tbl[j]={e,start,n}, 64 gathered rows x
// 128 cols, K=512. All staging via gl16, double-buffered 2-phase pipeline.
// Wave tile 32x64: acc[2][4].
// ---------------------------------------------------------------------------
__global__ __launch_bounds__(256, 2) void k_gemm2g(
    const unsigned short* __restrict__ h, const unsigned short* __restrict__ wet,
    const float* __restrict__ be, const int* __restrict__ idx,
    const int* __restrict__ tbl, float* __restrict__ out)
{
    __shared__ unsigned short lsA[2][BM2 * 32];
    __shared__ unsigned short lsB[2][128 * 32];
    __shared__ int rowid[BM2];

    int bj = blockIdx.x;
    int e = tbl[bj * 3 + 0], s = tbl[bj * 3 + 1], n = tbl[bj * 3 + 2];
    if (n == 0) return;

    int t = threadIdx.x;
    int l = t & 63, wid = t >> 6;
    int wr = (wid >> 1) * 32, wc = (wid & 1) * 64;
    int lr = l & 15, kc = (l >> 4) * 8;

    if (t < BM2) rowid[t] = idx[s + (t < n ? t : n - 1)];
    __syncthreads();

    // A: wave wid stages rows [wid*16, wid*16+16) -> 1 gl16
    int arow = wid * 16 + (l >> 2);
    const unsigned short* asrc = h + (size_t)rowid[arow] * D_HC + (l & 3) * 8;
    // B: wave wid stages rows [wid*32, wid*32+32) -> 2 gl16
    const unsigned short* wbase = wet + (size_t)e * D_OC * D_HC;
    const unsigned short* bsrc0 =
        wbase + (size_t)(wid * 32 + (l >> 2)) * D_HC + (l & 3) * 8;
    const unsigned short* bsrc1 = bsrc0 + (size_t)16 * D_HC;

    f32x4 acc[2][4];
    #pragma unroll
    for (int i = 0; i < 2; i++)
        #pragma unroll
        for (int j = 0; j < 4; j++) acc[i][j] = (f32x4){0.f, 0.f, 0.f, 0.f};

    auto stage = [&](int buf, int k0) {
        gl16(asrc + k0, &lsA[buf][(wid * 16) * 32]);
        gl16(bsrc0 + k0, &lsB[buf][(wid * 32) * 32]);
        gl16(bsrc1 + k0, &lsB[buf][(wid * 32 + 16) * 32]);
    };

    stage(0, 0);
    __syncthreads();
    #pragma unroll 2
    for (int ks = 0; ks < 16; ks++) {
        int cur = ks & 1;
        if (ks < 15) stage(cur ^ 1, (ks + 1) * 32);   // issue early
        bf16x8 af[2], bfr[4];
        #pragma unroll
        for (int i = 0; i < 2; i++)
            af[i]  = __builtin_bit_cast(bf16x8, *(const u32x4*)&lsA[cur][(wr + i * 16 + lr) * 32 + kc]);
        #pragma unroll
        for (int j = 0; j < 4; j++)
            bfr[j] = __builtin_bit_cast(bf16x8, *(const u32x4*)&lsB[cur][(wc + j * 16 + lr) * 32 + kc]);
        #pragma unroll
        for (int i = 0; i < 2; i++)
            #pragma unroll
            for (int j = 0; j < 4; j++)
                acc[i][j] = mfma_bf16(af[i], bfr[j], acc[i][j]);
        __syncthreads();
    }

    #pragma unroll
    for (int j = 0; j < 4; j++) {
        int col = wc + j * 16 + lr;
        float bev = be[e * D_OC + col];
        #pragma unroll
        for (int i = 0; i < 2; i++) {
            int rl = wr + i * 16 + (l >> 4) * 4;
            #pragma unroll
            for (int r = 0; r < 4; r++) {
                if (rl + r < n) {
                    float v = acc[i][j][r] + bev;
                    out[(size_t)rowid[rl + r] * D_OC + col] = 1.f / (1.f + __expf(-v));
                }
            }
        }
    }
}

// ---------------------------------------------------------------------------
extern "C" void kernel_launch(void* const* d_in, const int* in_sizes, int n_in,
                              void* d_out, int out_size, void* d_ws, size_t ws_size,
                              hipStream_t stream)
{
    const float* x  = (const float*)d_in[0];
    const int* num  = (const int*)d_in[1];
    const int* c    = (const int*)d_in[2];
    const float* W1 = (const float*)d_in[3];
    const float* b1 = (const float*)d_in[4];
    const float* We = (const float*)d_in[5];
    const float* be = (const float*)d_in[6];
    float* out = (float*)d_out;

    uint8_t* p = (uint8_t*)d_ws;
    unsigned short* w1t  = (unsigned short*)p;  p += (size_t)512 * 512 * 2;
    unsigned short* wet  = (unsigned short*)p;  p += (size_t)16 * 128 * 512 * 2;
    unsigned short* hbuf = (unsigned short*)p;  p += (size_t)BROWS * 512 * 2;
    int* cnt  = (int*)p;  p += N_EXPC * 4;
    int* base = (int*)p;  p += N_EXPC * 4;
    int* tbl  = (int*)p;  p += MAXTILES * 3 * 4;
    int* idx  = (int*)p;  p += (size_t)BROWS * 4;

    dim3 b256(256);
    hipMemsetAsync(cnt, 0, N_EXPC * sizeof(int), stream);
    k_hist<<<dim3(256), b256, 0, stream>>>(num, c, cnt);
    k_scan<<<dim3(1), dim3(64), 0, stream>>>(cnt, base, tbl);
    k_scatter<<<dim3(256), b256, 0, stream>>>(num, c, base, idx);
    k_transpose_bf16<<<dim3(8, 8, 1), b256, 0, stream>>>(W1, w1t, 512, 512, 0, 0);
    k_transpose_bf16<<<dim3(8, 2, 16), b256, 0, stream>>>(We, wet, 512, 128,
                                                          (long)512 * 128, (long)512 * 128);
    k_gemm1<<<dim3(2048), b256, 0, stream>>>(x, w1t, b1, hbuf);
    k_gemm2g<<<dim3(MAXTILES), b256, 0, stream>>>(hbuf, wet, be, idx, tbl, out);
}